// Round 16
// baseline (124.452 us; speedup 1.0000x reference)
//
#include <hip/hip_runtime.h>

namespace {
constexpr int kB    = 8;
constexpr int kC    = 64;
constexpr int kH    = 64, kW = 64;
constexpr int kNP   = 8192;             // positions
constexpr int kC1In = 1092;
constexpr int kKP   = 1152;             // padded K for GEMM1 (18 x 64)
constexpr int kC1Out= 313;
constexpr int kC2Out= 3136;
constexpr int kC1P  = 320;              // padded C1Out
constexpr int kRowS = 56;               // fp16 per (pos,n) row: 49 + 7 zero pad
constexpr int kPosS = 16 * kRowS + 8;   // 904 fp16 per pos
constexpr int kHStS = 328;              // hst LDS row stride (ushort): bank spread
// merged pre-kernel block ranges
constexpr int kPreFeat = 2048;          // 4 g x 512 ptiles
constexpr int kPreW2   = 490;           // 125440 / 256
constexpr int kPreW1   = 1440;          // 368640 / 256
constexpr int kPreBlocks = kPreFeat + kPreW2 + kPreW1;   // 3978
}

typedef __attribute__((ext_vector_type(8))) short bf16x8;
typedef __attribute__((ext_vector_type(8))) _Float16 f16x8;
typedef __attribute__((ext_vector_type(2))) _Float16 h16x2;
typedef __attribute__((ext_vector_type(4))) float f32x4;

__device__ __forceinline__ unsigned short f2bf(float f) {
    unsigned u = __float_as_uint(f);
    unsigned r = (u + 0x7fffu + ((u >> 16) & 1u)) >> 16;   // RNE
    return (unsigned short)r;
}
__device__ __forceinline__ float bf2f(unsigned short h) {
    return __uint_as_float(((unsigned)h) << 16);
}

// ---------------- K_pre: feat | w2split | w1cvt(+stat zero) by block range --
__global__ __launch_bounds__(256) void k_pre(const float* __restrict__ x,
        const float* __restrict__ w1, const float* __restrict__ w2,
        unsigned short* __restrict__ feat_bf, unsigned short* __restrict__ w1s,
        bf16x8* __restrict__ w2t, float* __restrict__ stats) {
    __shared__ float xs[16 * 7 * 40];   // 11.2 KB (feat branch only)
    int tid = threadIdx.x;
    int bid = blockIdx.x;

    if (bid < kPreFeat) {               // ---- feat ----
        int g = bid >> 9, pt = bid & 511;
        int p0 = pt * 16;
        int b = p0 >> 10, i = (p0 >> 5) & 31, j0 = p0 & 31;
        int y0 = 2 * i - 3, xbase = 2 * j0 - 3;
        const float* xb = x + ((size_t)(b * 64 + g * 16) << 12);

        for (int idx = tid; idx < 16 * 7 * 40; idx += 256) {
            int ch = idx / 280, r2 = idx - ch * 280;
            int row = r2 / 40, col = r2 - row * 40;
            int yy = y0 + row, xx = xbase + col;
            float v = 0.f;
            if ((unsigned)yy < 64u && (unsigned)xx < 64u)
                v = xb[(ch << 12) + (yy << 6) + xx];
            xs[idx] = v;
        }
        __syncthreads();

        for (int o = tid; o < 16 * 273; o += 256) {
            int pos = o / 273, c = o - pos * 273;
            float m = -INFINITY;
            int cg;
            if (c < 49) {
                int a = c / 7, bk = c - a * 7;
                int base = a * 40 + 2 * pos + bk;
                #pragma unroll
                for (int ch = 0; ch < 16; ++ch) m = fmaxf(m, xs[ch * 280 + base]);
                cg = g * 49 + c;
            } else if (c < 161) {
                int r = c - 49;
                int ch = r / 7, bk = r - ch * 7;
                int base = ch * 280 + 2 * pos + bk;
                #pragma unroll
                for (int a = 0; a < 7; ++a) m = fmaxf(m, xs[base + a * 40]);
                cg = 196 + g * 112 + r;
            } else {
                int r = c - 161;
                int ch = r / 7, a = r - ch * 7;
                int base = ch * 280 + a * 40 + 2 * pos;
                #pragma unroll
                for (int bk = 0; bk < 7; ++bk) m = fmaxf(m, xs[base + bk]);
                cg = 644 + g * 112 + r;
            }
            feat_bf[(size_t)(p0 + pos) * kKP + cg] = f2bf(m);
        }
        if (g == 3) {   // zero-fill K-pad [1092,1152)
            for (int idx = tid; idx < 16 * 60; idx += 256) {
                int pos = idx / 60, c = idx - pos * 60;
                feat_bf[(size_t)(p0 + pos) * kKP + 1092 + c] = 0;
            }
        }
    } else if (bid < kPreFeat + kPreW2) {   // ---- w2split (16x16 frag layout) ----
        int idx = (bid - kPreFeat) * 256 + tid;   // < 125440
        int lane = idx & 63;
        int t = (idx >> 6) % 10;
        int k = (idx / 640) % 49;
        int g = idx / 31360;
        int n = lane & 15, c0 = t * 32 + ((lane >> 4) << 3);
        int row = g * 784 + k * 16 + n;
        bf16x8 hi;
        #pragma unroll
        for (int e = 0; e < 8; ++e) {
            int c = c0 + e;
            float v = (c < kC1Out) ? w2[(size_t)row * kC1Out + c] : 0.f;
            hi[e] = (short)f2bf(v);
        }
        w2t[idx] = hi;
    } else {                                 // ---- w1cvt + stat zero ----
        int idx = (bid - kPreFeat - kPreW2) * 256 + tid;   // < 368640
        if (idx < 640) stats[idx] = 0.f;
        int r = idx / kKP, c = idx - r * kKP;
        float v = (r < kC1Out && c < kC1In) ? w1[(size_t)r * kC1In + c] : 0.f;
        w1s[idx] = f2bf(v);
    }
}

// ---------------- K2: MFMA GEMM1, BM=128 BN=64 BK=64, 8 waves (4x2) --------
// h stored bf16 [pos][320] (halves h write traffic; BN applied in k_fused).
__global__ __launch_bounds__(512) void k_gemm1(
        const unsigned short* __restrict__ feat_bf, const unsigned short* __restrict__ w1s,
        unsigned short* __restrict__ hb16, float* __restrict__ sum_, float* __restrict__ sumsq_) {
    __shared__ unsigned short Ald[128 * 64];   // 16 KB
    __shared__ unsigned short Bld[64 * 64];    // 8 KB
    __shared__ float lsum[64], lsq[64];
    int tid = threadIdx.x;
    int lane = tid & 63, wv = tid >> 6;        // wv 0..7
    int row0 = blockIdx.x * 128, col0 = blockIdx.y * 64;
    int wr = wv >> 1, wc = wv & 1;             // 4 x 2 wave grid
    int srow = lane >> 3;
    int soct = (lane & 7) ^ srow;
    int frow = lane & 15, fk = lane >> 4;

    f32x4 acc[2][2] = {};
    for (int k0 = 0; k0 < kKP; k0 += 64) {
        #pragma unroll
        for (int qq = 0; qq < 3; ++qq) {       // 24 chunks: 16 A + 8 B
            int q = wv + qq * 8;
            const unsigned short* srcbase;
            unsigned short* dst;
            int grow;
            if (q < 16) { grow = row0 + q * 8 + srow; srcbase = feat_bf; dst = Ald + q * 512; }
            else        { grow = col0 + (q - 16) * 8 + srow; srcbase = w1s; dst = Bld + (q - 16) * 512; }
            const unsigned short* src = srcbase + (size_t)grow * kKP + k0 + soct * 8;
            __builtin_amdgcn_global_load_lds(
                (const __attribute__((address_space(1))) unsigned int*)src,
                (__attribute__((address_space(3))) unsigned int*)dst, 16, 0, 0);
        }
        __syncthreads();
        #pragma unroll
        for (int ks = 0; ks < 2; ++ks) {
            int oct = ks * 4 + fk;
            bf16x8 a0, a1, b0, b1;
            { int r = wr * 32 + frow;      a0 = *(const bf16x8*)(Ald + (r * 8 + (oct ^ (r & 7))) * 8); }
            { int r = wr * 32 + 16 + frow; a1 = *(const bf16x8*)(Ald + (r * 8 + (oct ^ (r & 7))) * 8); }
            { int r = wc * 32 + frow;      b0 = *(const bf16x8*)(Bld + (r * 8 + (oct ^ (r & 7))) * 8); }
            { int r = wc * 32 + 16 + frow; b1 = *(const bf16x8*)(Bld + (r * 8 + (oct ^ (r & 7))) * 8); }
            acc[0][0] = __builtin_amdgcn_mfma_f32_16x16x32_bf16(a0, b0, acc[0][0], 0, 0, 0);
            acc[0][1] = __builtin_amdgcn_mfma_f32_16x16x32_bf16(a0, b1, acc[0][1], 0, 0, 0);
            acc[1][0] = __builtin_amdgcn_mfma_f32_16x16x32_bf16(a1, b0, acc[1][0], 0, 0, 0);
            acc[1][1] = __builtin_amdgcn_mfma_f32_16x16x32_bf16(a1, b1, acc[1][1], 0, 0, 0);
        }
        __syncthreads();
    }

    if (tid < 64) { lsum[tid] = 0.f; lsq[tid] = 0.f; }
    __syncthreads();
    #pragma unroll
    for (int i = 0; i < 2; ++i) {
        int mrow = row0 + wr * 32 + i * 16 + (lane >> 4) * 4;
        #pragma unroll
        for (int j = 0; j < 2; ++j) {
            int col_l = wc * 32 + j * 16 + (lane & 15);
            float s = 0.f, sq = 0.f;
            #pragma unroll
            for (int r = 0; r < 4; ++r) {
                float v = acc[i][j][r];
                hb16[(size_t)(mrow + r) * kC1P + col0 + col_l] = f2bf(v);
                s += v; sq += v * v;
            }
            atomicAdd(&lsum[col_l], s);
            atomicAdd(&lsq[col_l], sq);
        }
    }
    __syncthreads();
    if (tid < 64 && col0 + tid < kC1Out) {
        atomicAdd(&sum_[col0 + tid], lsum[tid]);
        atomicAdd(&sumsq_[col0 + tid], lsq[tid]);
    }
}

// ---------------- K4: BN(in-block)+ReLU -> pair-slot MFMA GEMM2 -> softmax --
// h-bf16 slice staged reg->LDS at padded stride 328 (bank = pos*4 mod 32,
// spread -- fixes round-14's 32-way conflict); scale/shift computed once into
// LDS; BN+ReLU+repack -> htl (linear, conflict-free). k_split_h eliminated.
// GEMM = round-13 pair-slot (best-measured 59.6us variant), unchanged.
__global__ __launch_bounds__(512) void k_fused(
        const unsigned short* __restrict__ hb16,
        const float* __restrict__ sum_, const float* __restrict__ sumsq_,
        const float* __restrict__ gamma, const float* __restrict__ beta,
        const bf16x8* __restrict__ w2t, const float* __restrict__ b2,
        const float* __restrict__ x, float* __restrict__ out) {
    __shared__ _Float16 wtb[32 * kPosS];   // 57,856 B (aliased: hst 20,992 + scsh 2,560)
    __shared__ float invt[512];            // 2,048 B
    __shared__ bf16x8 htl[1280];           // 20,480 B -> total 80,384 B (2 blocks/CU)
    unsigned short* hst = (unsigned short*)wtb;          // [32][328]
    float* scsh = (float*)(wtb + 11000);                 // 640 f32 at byte 22,000
    int tid = threadIdx.x;
    int lane = tid & 63, wv = tid >> 6;
    int bid = blockIdx.x;
    int g = bid >> 8, pt = bid & 255;      // 32-position tile pt

    // ---- phase A: stage h-bf16 (coalesced) + compute scale/shift ----
    {
        const unsigned short* hb = hb16 + (size_t)pt * 32 * kC1P;
        for (int q = tid; q < 1280; q += 512) {
            int pos = q / 40, off = q - pos * 40;
            bf16x8 vfrag = *(const bf16x8*)(hb + pos * kC1P + off * 8);
            *(bf16x8*)(hst + pos * kHStS + off * 8) = vfrag;
        }
        if (tid < 320) {
            float mu  = sum_[tid]   * (1.f / kNP);
            float var = sumsq_[tid] * (1.f / kNP) - mu * mu;
            float sc  = (tid < kC1Out) ? gamma[tid] * rsqrtf(var + 1e-5f) : 0.f;
            scsh[tid] = sc;
            scsh[320 + tid] = (tid < kC1Out) ? beta[tid] - mu * sc : 0.f;
        }
    }
    __syncthreads();

    // ---- phase B: BN + ReLU + repack to htl 16x16-frag layout ----
    for (int v = tid; v < 1280; v += 512) {
        int lv = v & 63;
        int t = (v >> 6) % 10;
        int half = v / 640;
        int pos = half * 16 + (lv & 15);
        int c0 = t * 32 + ((lv >> 4) << 3);
        bf16x8 raw = *(const bf16x8*)(hst + pos * kHStS + c0);
        bf16x8 hi;
        #pragma unroll
        for (int e = 0; e < 8; ++e) {
            int c = c0 + e;
            float f = bf2f((unsigned short)raw[e]);
            float vo = (c < kC1Out) ? fmaxf(f * scsh[c] + scsh[320 + c], 0.f) : 0.f;
            hi[e] = (short)f2bf(vo);
        }
        htl[v] = hi;
    }
    __syncthreads();   // htl done; hst/scsh (wtb space) free for GEMM output

    // ---- GEMM2: round-13 pair-slot (k, k+8) ----
    int col = lane & 15, rgrp = lane >> 4;
    for (int k = wv; k < 49; k += 16) {
        int k2 = k + 8;
        bool has2 = (k2 < 49);
        int k2c = has2 ? k2 : k;           // clamp: duplicate work, discarded
        f32x4 acc00 = {0.f,0.f,0.f,0.f}, acc01 = {0.f,0.f,0.f,0.f};
        f32x4 acc10 = {0.f,0.f,0.f,0.f}, acc11 = {0.f,0.f,0.f,0.f};
        const bf16x8* wb0 = w2t + ((size_t)(g * 49 + k)   * 10) * 64 + lane;
        const bf16x8* wb1 = w2t + ((size_t)(g * 49 + k2c) * 10) * 64 + lane;
        bf16x8 bh0[10], bh1[10];
        #pragma unroll
        for (int t = 0; t < 10; ++t) { bh0[t] = wb0[t * 64]; bh1[t] = wb1[t * 64]; }
        #pragma unroll
        for (int t = 0; t < 10; ++t) {
            bf16x8 a0 = htl[t * 64 + lane];
            bf16x8 a1 = htl[640 + t * 64 + lane];
            acc00 = __builtin_amdgcn_mfma_f32_16x16x32_bf16(a0, bh0[t], acc00, 0, 0, 0);
            acc01 = __builtin_amdgcn_mfma_f32_16x16x32_bf16(a1, bh0[t], acc01, 0, 0, 0);
            acc10 = __builtin_amdgcn_mfma_f32_16x16x32_bf16(a0, bh1[t], acc10, 0, 0, 0);
            acc11 = __builtin_amdgcn_mfma_f32_16x16x32_bf16(a1, bh1[t], acc11, 0, 0, 0);
        }
        {
            float bias = b2[g * 784 + k * 16 + col];
            #pragma unroll
            for (int r = 0; r < 4; ++r) {
                int pos = rgrp * 4 + r;        // C: row=(lane>>4)*4+reg
                wtb[pos * kPosS + k * 16 + col]        = (_Float16)(acc00[r] + bias);
                wtb[(pos + 16) * kPosS + k * 16 + col] = (_Float16)(acc01[r] + bias);
            }
        }
        if (has2) {
            float bias = b2[g * 784 + k2 * 16 + col];
            #pragma unroll
            for (int r = 0; r < 4; ++r) {
                int pos = rgrp * 4 + r;
                wtb[pos * kPosS + k2 * 16 + col]        = (_Float16)(acc10[r] + bias);
                wtb[(pos + 16) * kPosS + k2 * 16 + col] = (_Float16)(acc11[r] + bias);
            }
        }
    }
    __syncthreads();

    // softmax per (pos, n): read layout A -> regs -> barrier -> write layout B
    {
        int pos = tid >> 4, n = tid & 15;
        const _Float16* baseA = wtb + pos * kPosS + n;
        f16x8 ee[7];
        float m = -INFINITY;
        #pragma unroll
        for (int c = 0; c < 7; ++c)
            #pragma unroll
            for (int e = 0; e < 8; ++e) {
                int k = c * 8 + e;
                if (k < 49) {
                    _Float16 v = baseA[k * 16];
                    ee[c][e] = v;
                    m = fmaxf(m, (float)v);
                } else ee[c][e] = (_Float16)0.f;
            }
        float s = 0.f;
        #pragma unroll
        for (int c = 0; c < 7; ++c)
            #pragma unroll
            for (int e = 0; e < 8; ++e) {
                int k = c * 8 + e;
                if (k < 49) {
                    float ex = __expf((float)ee[c][e] - m);
                    s += ex;
                    ee[c][e] = (_Float16)ex;
                }                                  // pads stay 0 -> dot2-safe
            }
        __syncthreads();                           // all A-reads done before B-writes
        _Float16* baseB = wtb + pos * kPosS + n * kRowS;
        #pragma unroll
        for (int c = 0; c < 7; ++c) *(f16x8*)(baseB + c * 8) = ee[c];
        invt[tid] = 1.f / (s * 49.f);
    }
    __syncthreads();

    // phase 4: thread = (pos fast, c16 slow)
    {
        int pos = tid & 31, c16 = tid >> 5;
        int p = pt * 32 + pos;
        int b = p >> 10, i = (p >> 5) & 31, j = p & 31;
        int y0 = 2 * i - 3, x0c = 2 * j - 3;
        const float* xc = x + (((size_t)b * 64 + g * 16 + c16) << 12);
        h16x2 patch2[28];
        #pragma unroll
        for (int a = 0; a < 7; ++a) {
            int yy = y0 + a;
            #pragma unroll
            for (int bk = 0; bk < 7; ++bk) {
                int kk = a * 7 + bk, xx = x0c + bk;
                float v = ((unsigned)yy < 64u && (unsigned)xx < 64u)
                        ? xc[(yy << 6) + xx] : 0.f;
                patch2[kk >> 1][kk & 1] = (_Float16)v;
            }
        }
        patch2[24][1] = (_Float16)0.f;   // k=49..55 zero
        patch2[25] = (h16x2)(_Float16)0.f;
        patch2[26] = (h16x2)(_Float16)0.f;
        patch2[27] = (h16x2)(_Float16)0.f;

        const _Float16* prow = wtb + pos * kPosS;
        float* outb = out + (((size_t)b * 64 + g * 16 + c16) << 14);
        #pragma unroll
        for (int n1 = 0; n1 < 4; ++n1) {
            f32x4 st;
            #pragma unroll
            for (int n2 = 0; n2 < 4; ++n2) {
                int n = n1 * 4 + n2;
                const f16x8* row = (const f16x8*)(prow + n * kRowS);
                float acc = 0.f;
                #pragma unroll
                for (int c = 0; c < 7; ++c) {
                    f16x8 w = row[c];
                    #pragma unroll
                    for (int q = 0; q < 4; ++q) {
                        h16x2 wp; wp[0] = w[2 * q]; wp[1] = w[2 * q + 1];
                        acc = __builtin_amdgcn_fdot2(patch2[c * 4 + q], wp, acc, false);
                    }
                }
                st[n2] = acc * invt[pos * 16 + n];
            }
            *(f32x4*)(outb + (i * 4 + n1) * 128 + j * 4) = st;
        }
    }
}

extern "C" void kernel_launch(void* const* d_in, const int* in_sizes, int n_in,
                              void* d_out, int out_size, void* d_ws, size_t ws_size,
                              hipStream_t stream) {
    const float* x     = (const float*)d_in[0];
    const float* w1    = (const float*)d_in[1];
    const float* gamma = (const float*)d_in[2];
    const float* beta  = (const float*)d_in[3];
    const float* w2    = (const float*)d_in[4];
    const float* b2    = (const float*)d_in[5];
    float* out = (float*)d_out;

    float* ws = (float*)d_ws;
    unsigned short* feat_bf = (unsigned short*)ws;        // 4,718,592 fl
    unsigned short* hb16 = (unsigned short*)(ws + 4718592);   // 8192*320 us = 1,310,720 fl
    float* w2t_f   = ws + 4718592 + 1310720;              // 501,760 fl
    unsigned short* w1s = (unsigned short*)(w2t_f + 501760);  // 184,320 fl
    float* sum_   = w2t_f + 501760 + 184320;
    float* sumsq_ = sum_ + 320;

    bf16x8* w2t = (bf16x8*)w2t_f;

    k_pre<<<kPreBlocks, 256, 0, stream>>>(x, w1, w2, feat_bf, w1s, w2t, sum_);
    k_gemm1<<<dim3(kNP / 128, 5), 512, 0, stream>>>(feat_bf, w1s, hb16, sum_, sumsq_);
    k_fused<<<1024, 512, 0, stream>>>(hb16, sum_, sumsq_, gamma, beta, w2t, b2, x, out);
}

// Round 17
// 109.097 us; speedup vs baseline: 1.1407x; 1.1407x over previous
//
#include <hip/hip_runtime.h>

namespace {
constexpr int kB    = 8;
constexpr int kC    = 64;
constexpr int kH    = 64, kW = 64;
constexpr int kNP   = 8192;             // positions
constexpr int kC1In = 1092;
constexpr int kKP   = 1152;             // padded K for GEMM1 (18 x 64)
constexpr int kC1Out= 313;
constexpr int kC2Out= 3136;
constexpr int kC1P  = 320;              // padded C1Out
constexpr int kRowS = 56;               // fp16 per (pos,n) row: 49 + 7 zero pad
constexpr int kPosS = 16 * kRowS + 8;   // 904 fp16 per pos
// merged pre-kernel block ranges
constexpr int kPreFeat = 2048;          // 4 g x 512 ptiles
constexpr int kPreW2   = 490;           // 125440 / 256
constexpr int kPreW1   = 1440;          // 368640 / 256
constexpr int kPreBlocks = kPreFeat + kPreW2 + kPreW1;   // 3978
}

typedef __attribute__((ext_vector_type(8))) short bf16x8;
typedef __attribute__((ext_vector_type(8))) _Float16 f16x8;
typedef __attribute__((ext_vector_type(2))) _Float16 h16x2;
typedef __attribute__((ext_vector_type(4))) float f32x4;

__device__ __forceinline__ unsigned short f2bf(float f) {
    unsigned u = __float_as_uint(f);
    unsigned r = (u + 0x7fffu + ((u >> 16) & 1u)) >> 16;   // RNE
    return (unsigned short)r;
}
__device__ __forceinline__ float bf2f(unsigned short h) {
    return __uint_as_float(((unsigned)h) << 16);
}

// ---------------- K_pre: feat | w2split | w1cvt(+stat zero) by block range --
__global__ __launch_bounds__(256) void k_pre(const float* __restrict__ x,
        const float* __restrict__ w1, const float* __restrict__ w2,
        unsigned short* __restrict__ feat_bf, unsigned short* __restrict__ w1s,
        bf16x8* __restrict__ w2t, float* __restrict__ stats) {
    __shared__ float xs[16 * 7 * 40];   // 11.2 KB (feat branch only)
    int tid = threadIdx.x;
    int bid = blockIdx.x;

    if (bid < kPreFeat) {               // ---- feat ----
        int g = bid >> 9, pt = bid & 511;
        int p0 = pt * 16;
        int b = p0 >> 10, i = (p0 >> 5) & 31, j0 = p0 & 31;
        int y0 = 2 * i - 3, xbase = 2 * j0 - 3;
        const float* xb = x + ((size_t)(b * 64 + g * 16) << 12);

        for (int idx = tid; idx < 16 * 7 * 40; idx += 256) {
            int ch = idx / 280, r2 = idx - ch * 280;
            int row = r2 / 40, col = r2 - row * 40;
            int yy = y0 + row, xx = xbase + col;
            float v = 0.f;
            if ((unsigned)yy < 64u && (unsigned)xx < 64u)
                v = xb[(ch << 12) + (yy << 6) + xx];
            xs[idx] = v;
        }
        __syncthreads();

        for (int pos = 0; pos < 16; ++pos) {
            for (int c = tid; c < 273; c += 256) {
                float m = -INFINITY;
                int cg;
                if (c < 49) {
                    int a = c / 7, bk = c - a * 7;
                    int base = a * 40 + 2 * pos + bk;
                    #pragma unroll
                    for (int ch = 0; ch < 16; ++ch) m = fmaxf(m, xs[ch * 280 + base]);
                    cg = g * 49 + c;
                } else if (c < 161) {
                    int r = c - 49;
                    int ch = r / 7, bk = r - ch * 7;
                    int base = ch * 280 + 2 * pos + bk;
                    #pragma unroll
                    for (int a = 0; a < 7; ++a) m = fmaxf(m, xs[base + a * 40]);
                    cg = 196 + g * 112 + r;
                } else {
                    int r = c - 161;
                    int ch = r / 7, a = r - ch * 7;
                    int base = ch * 280 + a * 40 + 2 * pos;
                    #pragma unroll
                    for (int bk = 0; bk < 7; ++bk) m = fmaxf(m, xs[base + bk]);
                    cg = 644 + g * 112 + r;
                }
                feat_bf[(size_t)(p0 + pos) * kKP + cg] = f2bf(m);
            }
        }
        if (g == 3) {   // zero-fill K-pad [1092,1152)
            for (int idx = tid; idx < 16 * 60; idx += 256) {
                int pos = idx / 60, c = idx - pos * 60;
                feat_bf[(size_t)(p0 + pos) * kKP + 1092 + c] = 0;
            }
        }
    } else if (bid < kPreFeat + kPreW2) {   // ---- w2split (16x16 frag layout) ----
        int idx = (bid - kPreFeat) * 256 + tid;   // < 125440
        int lane = idx & 63;
        int t = (idx >> 6) % 10;
        int k = (idx / 640) % 49;
        int g = idx / 31360;
        int n = lane & 15, c0 = t * 32 + ((lane >> 4) << 3);
        int row = g * 784 + k * 16 + n;
        bf16x8 hi;
        #pragma unroll
        for (int e = 0; e < 8; ++e) {
            int c = c0 + e;
            float v = (c < kC1Out) ? w2[(size_t)row * kC1Out + c] : 0.f;
            hi[e] = (short)f2bf(v);
        }
        w2t[idx] = hi;
    } else {                                 // ---- w1cvt + stat zero ----
        int idx = (bid - kPreFeat - kPreW2) * 256 + tid;   // < 368640
        if (idx < 640) stats[idx] = 0.f;
        int r = idx / kKP, c = idx - r * kKP;
        float v = (r < kC1Out && c < kC1In) ? w1[(size_t)r * kC1In + c] : 0.f;
        w1s[idx] = f2bf(v);
    }
}

// ---------------- K2: MFMA GEMM1, BM=128 BN=64 BK=64, 8 waves (4x2) --------
// h stored bf16 (halves write traffic; round-16 proved absmax unchanged).
// Stats shuffle-reduced across row-groups before LDS atomics (8 -> ~2/thread).
__global__ __launch_bounds__(512) void k_gemm1(
        const unsigned short* __restrict__ feat_bf, const unsigned short* __restrict__ w1s,
        unsigned short* __restrict__ hb16, float* __restrict__ sum_, float* __restrict__ sumsq_) {
    __shared__ unsigned short Ald[128 * 64];   // 16 KB
    __shared__ unsigned short Bld[64 * 64];    // 8 KB
    __shared__ float lsum[64], lsq[64];
    int tid = threadIdx.x;
    int lane = tid & 63, wv = tid >> 6;        // wv 0..7
    int row0 = blockIdx.x * 128, col0 = blockIdx.y * 64;
    int wr = wv >> 1, wc = wv & 1;             // 4 x 2 wave grid
    int srow = lane >> 3;
    int soct = (lane & 7) ^ srow;
    int frow = lane & 15, fk = lane >> 4;

    f32x4 acc[2][2] = {};
    for (int k0 = 0; k0 < kKP; k0 += 64) {
        #pragma unroll
        for (int qq = 0; qq < 3; ++qq) {       // 24 chunks: 16 A + 8 B
            int q = wv + qq * 8;
            const unsigned short* srcbase;
            unsigned short* dst;
            int grow;
            if (q < 16) { grow = row0 + q * 8 + srow; srcbase = feat_bf; dst = Ald + q * 512; }
            else        { grow = col0 + (q - 16) * 8 + srow; srcbase = w1s; dst = Bld + (q - 16) * 512; }
            const unsigned short* src = srcbase + (size_t)grow * kKP + k0 + soct * 8;
            __builtin_amdgcn_global_load_lds(
                (const __attribute__((address_space(1))) unsigned int*)src,
                (__attribute__((address_space(3))) unsigned int*)dst, 16, 0, 0);
        }
        __syncthreads();
        #pragma unroll
        for (int ks = 0; ks < 2; ++ks) {
            int oct = ks * 4 + fk;
            bf16x8 a0, a1, b0, b1;
            { int r = wr * 32 + frow;      a0 = *(const bf16x8*)(Ald + (r * 8 + (oct ^ (r & 7))) * 8); }
            { int r = wr * 32 + 16 + frow; a1 = *(const bf16x8*)(Ald + (r * 8 + (oct ^ (r & 7))) * 8); }
            { int r = wc * 32 + frow;      b0 = *(const bf16x8*)(Bld + (r * 8 + (oct ^ (r & 7))) * 8); }
            { int r = wc * 32 + 16 + frow; b1 = *(const bf16x8*)(Bld + (r * 8 + (oct ^ (r & 7))) * 8); }
            acc[0][0] = __builtin_amdgcn_mfma_f32_16x16x32_bf16(a0, b0, acc[0][0], 0, 0, 0);
            acc[0][1] = __builtin_amdgcn_mfma_f32_16x16x32_bf16(a0, b1, acc[0][1], 0, 0, 0);
            acc[1][0] = __builtin_amdgcn_mfma_f32_16x16x32_bf16(a1, b0, acc[1][0], 0, 0, 0);
            acc[1][1] = __builtin_amdgcn_mfma_f32_16x16x32_bf16(a1, b1, acc[1][1], 0, 0, 0);
        }
        __syncthreads();
    }

    if (tid < 64) { lsum[tid] = 0.f; lsq[tid] = 0.f; }
    __syncthreads();
    #pragma unroll
    for (int j = 0; j < 2; ++j) {
        int col_l = wc * 32 + j * 16 + (lane & 15);
        float s = 0.f, sq = 0.f;
        #pragma unroll
        for (int i = 0; i < 2; ++i) {
            int mrow = row0 + wr * 32 + i * 16 + (lane >> 4) * 4;
            #pragma unroll
            for (int r = 0; r < 4; ++r) {
                float v = acc[i][j][r];
                hb16[(size_t)(mrow + r) * kC1P + col0 + col_l] = f2bf(v);
                s += v; sq += v * v;
            }
        }
        s  += __shfl_xor(s, 16);  s  += __shfl_xor(s, 32);
        sq += __shfl_xor(sq, 16); sq += __shfl_xor(sq, 32);
        if (lane < 16) {
            atomicAdd(&lsum[col_l], s);
            atomicAdd(&lsq[col_l], sq);
        }
    }
    __syncthreads();
    if (tid < 64 && col0 + tid < kC1Out) {
        atomicAdd(&sum_[col0 + tid], lsum[tid]);
        atomicAdd(&sumsq_[col0 + tid], lsq[tid]);
    }
}

// ---------------- K4a: BN(inline finalize)+ReLU hb16 -> frag-ready bf16 ----
__global__ void k_split_h(const unsigned short* __restrict__ hb16,
                          const float* __restrict__ sum_, const float* __restrict__ sumsq_,
                          const float* __restrict__ gamma, const float* __restrict__ beta,
                          bf16x8* __restrict__ ht_hi) {
    int idx = blockIdx.x * 256 + threadIdx.x;   // 512*10*64 = 327680
    int lane = idx & 63;
    int t = (idx >> 6) % 10;
    int ptile = idx / 640;
    int pos = ptile * 16 + (lane & 15);
    int c0 = t * 32 + ((lane >> 4) << 3);
    bf16x8 raw = *(const bf16x8*)(hb16 + (size_t)pos * kC1P + c0);
    bf16x8 hi;
    #pragma unroll
    for (int e = 0; e < 8; ++e) {
        int c = c0 + e;
        float v = 0.f;
        if (c < kC1Out) {
            float mu  = sum_[c]   * (1.f / kNP);
            float var = sumsq_[c] * (1.f / kNP) - mu * mu;
            float sc  = gamma[c] * rsqrtf(var + 1e-5f);
            float sh  = beta[c] - mu * sc;
            v = fmaxf(bf2f((unsigned short)raw[e]) * sc + sh, 0.f);
        }
        hi[e] = (short)f2bf(v);
    }
    ht_hi[idx] = hi;
}

// ---------------- K4b: pair-slot MFMA GEMM2 -> softmax(49) -> fdot2 --------
// Round-13 exact (best-measured 59.6us): htl staged via global_load_lds,
// pair-slot (k, k+8) GEMM, layout A writes, softmax A->regs->B, invt table,
// phase 4 pos-fast with fdot2.
__global__ __launch_bounds__(512) void k_fused(
        const bf16x8* __restrict__ ht_hi, const bf16x8* __restrict__ w2t,
        const float* __restrict__ b2, const float* __restrict__ x,
        float* __restrict__ out) {
    __shared__ _Float16 wtb[32 * kPosS];   // 57,856 B
    __shared__ float invt[512];            // 2,048 B
    __shared__ bf16x8 htl[1280];           // 20,480 B -> total 80,384 B
    int tid = threadIdx.x;
    int lane = tid & 63, wv = tid >> 6;
    int bid = blockIdx.x;
    int g = bid >> 8, pt = bid & 255;      // 32-position tile pt

    // stage ht (both 16-pos halves) linearly into LDS
    {
        const bf16x8* hb = ht_hi + (size_t)(pt * 2) * 640;
        #pragma unroll
        for (int r = 0; r < 3; ++r) {
            int idx = r * 512 + tid;
            if (idx < 1280)
                __builtin_amdgcn_global_load_lds(
                    (const __attribute__((address_space(1))) unsigned int*)(hb + idx),
                    (__attribute__((address_space(3))) unsigned int*)(htl + idx), 16, 0, 0);
        }
    }
    __syncthreads();

    int col = lane & 15, rgrp = lane >> 4;
    for (int k = wv; k < 49; k += 16) {
        int k2 = k + 8;
        bool has2 = (k2 < 49);
        int k2c = has2 ? k2 : k;           // clamp: duplicate work, discarded
        f32x4 acc00 = {0.f,0.f,0.f,0.f}, acc01 = {0.f,0.f,0.f,0.f};
        f32x4 acc10 = {0.f,0.f,0.f,0.f}, acc11 = {0.f,0.f,0.f,0.f};
        const bf16x8* wb0 = w2t + ((size_t)(g * 49 + k)   * 10) * 64 + lane;
        const bf16x8* wb1 = w2t + ((size_t)(g * 49 + k2c) * 10) * 64 + lane;
        bf16x8 bh0[10], bh1[10];
        #pragma unroll
        for (int t = 0; t < 10; ++t) { bh0[t] = wb0[t * 64]; bh1[t] = wb1[t * 64]; }
        #pragma unroll
        for (int t = 0; t < 10; ++t) {
            bf16x8 a0 = htl[t * 64 + lane];
            bf16x8 a1 = htl[640 + t * 64 + lane];
            acc00 = __builtin_amdgcn_mfma_f32_16x16x32_bf16(a0, bh0[t], acc00, 0, 0, 0);
            acc01 = __builtin_amdgcn_mfma_f32_16x16x32_bf16(a1, bh0[t], acc01, 0, 0, 0);
            acc10 = __builtin_amdgcn_mfma_f32_16x16x32_bf16(a0, bh1[t], acc10, 0, 0, 0);
            acc11 = __builtin_amdgcn_mfma_f32_16x16x32_bf16(a1, bh1[t], acc11, 0, 0, 0);
        }
        {
            float bias = b2[g * 784 + k * 16 + col];
            #pragma unroll
            for (int r = 0; r < 4; ++r) {
                int pos = rgrp * 4 + r;        // C: row=(lane>>4)*4+reg
                wtb[pos * kPosS + k * 16 + col]        = (_Float16)(acc00[r] + bias);
                wtb[(pos + 16) * kPosS + k * 16 + col] = (_Float16)(acc01[r] + bias);
            }
        }
        if (has2) {
            float bias = b2[g * 784 + k2 * 16 + col];
            #pragma unroll
            for (int r = 0; r < 4; ++r) {
                int pos = rgrp * 4 + r;
                wtb[pos * kPosS + k2 * 16 + col]        = (_Float16)(acc10[r] + bias);
                wtb[(pos + 16) * kPosS + k2 * 16 + col] = (_Float16)(acc11[r] + bias);
            }
        }
    }
    __syncthreads();

    // softmax per (pos, n): read layout A -> regs -> barrier -> write layout B
    {
        int pos = tid >> 4, n = tid & 15;
        const _Float16* baseA = wtb + pos * kPosS + n;
        f16x8 ee[7];
        float m = -INFINITY;
        #pragma unroll
        for (int c = 0; c < 7; ++c)
            #pragma unroll
            for (int e = 0; e < 8; ++e) {
                int k = c * 8 + e;
                if (k < 49) {
                    _Float16 v = baseA[k * 16];
                    ee[c][e] = v;
                    m = fmaxf(m, (float)v);
                } else ee[c][e] = (_Float16)0.f;
            }
        float s = 0.f;
        #pragma unroll
        for (int c = 0; c < 7; ++c)
            #pragma unroll
            for (int e = 0; e < 8; ++e) {
                int k = c * 8 + e;
                if (k < 49) {
                    float ex = __expf((float)ee[c][e] - m);
                    s += ex;
                    ee[c][e] = (_Float16)ex;
                }                                  // pads stay 0 -> dot2-safe
            }
        __syncthreads();                           // all A-reads done before B-writes
        _Float16* baseB = wtb + pos * kPosS + n * kRowS;
        #pragma unroll
        for (int c = 0; c < 7; ++c) *(f16x8*)(baseB + c * 8) = ee[c];
        invt[tid] = 1.f / (s * 49.f);
    }
    __syncthreads();

    // phase 4: thread = (pos fast, c16 slow)
    {
        int pos = tid & 31, c16 = tid >> 5;
        int p = pt * 32 + pos;
        int b = p >> 10, i = (p >> 5) & 31, j = p & 31;
        int y0 = 2 * i - 3, x0c = 2 * j - 3;
        const float* xc = x + (((size_t)b * 64 + g * 16 + c16) << 12);
        h16x2 patch2[28];
        #pragma unroll
        for (int a = 0; a < 7; ++a) {
            int yy = y0 + a;
            #pragma unroll
            for (int bk = 0; bk < 7; ++bk) {
                int kk = a * 7 + bk, xx = x0c + bk;
                float v = ((unsigned)yy < 64u && (unsigned)xx < 64u)
                        ? xc[(yy << 6) + xx] : 0.f;
                patch2[kk >> 1][kk & 1] = (_Float16)v;
            }
        }
        patch2[24][1] = (_Float16)0.f;   // k=49..55 zero
        patch2[25] = (h16x2)(_Float16)0.f;
        patch2[26] = (h16x2)(_Float16)0.f;
        patch2[27] = (h16x2)(_Float16)0.f;

        const _Float16* prow = wtb + pos * kPosS;
        float* outb = out + (((size_t)b * 64 + g * 16 + c16) << 14);
        #pragma unroll
        for (int n1 = 0; n1 < 4; ++n1) {
            f32x4 st;
            #pragma unroll
            for (int n2 = 0; n2 < 4; ++n2) {
                int n = n1 * 4 + n2;
                const f16x8* row = (const f16x8*)(prow + n * kRowS);
                float acc = 0.f;
                #pragma unroll
                for (int c = 0; c < 7; ++c) {
                    f16x8 w = row[c];
                    #pragma unroll
                    for (int q = 0; q < 4; ++q) {
                        h16x2 wp; wp[0] = w[2 * q]; wp[1] = w[2 * q + 1];
                        acc = __builtin_amdgcn_fdot2(patch2[c * 4 + q], wp, acc, false);
                    }
                }
                st[n2] = acc * invt[pos * 16 + n];
            }
            *(f32x4*)(outb + (i * 4 + n1) * 128 + j * 4) = st;
        }
    }
}

extern "C" void kernel_launch(void* const* d_in, const int* in_sizes, int n_in,
                              void* d_out, int out_size, void* d_ws, size_t ws_size,
                              hipStream_t stream) {
    const float* x     = (const float*)d_in[0];
    const float* w1    = (const float*)d_in[1];
    const float* gamma = (const float*)d_in[2];
    const float* beta  = (const float*)d_in[3];
    const float* w2    = (const float*)d_in[4];
    const float* b2    = (const float*)d_in[5];
    float* out = (float*)d_out;

    float* ws = (float*)d_ws;
    unsigned short* feat_bf = (unsigned short*)ws;            // 4,718,592 fl-equiv
    unsigned short* hb16 = (unsigned short*)(ws + 4718592);   // 8192*320 us = 1,310,720 fl
    float* w2t_f   = ws + 4718592 + 1310720;                  // 501,760 fl
    unsigned short* w1s = (unsigned short*)(w2t_f + 501760);  // 184,320 fl
    float* sum_   = w2t_f + 501760 + 184320;
    float* sumsq_ = sum_ + 320;

    bf16x8* ht_hi = (bf16x8*)ws;                              // reuses feat region
    bf16x8* w2t   = (bf16x8*)w2t_f;

    k_pre<<<kPreBlocks, 256, 0, stream>>>(x, w1, w2, feat_bf, w1s, w2t, sum_);
    k_gemm1<<<dim3(kNP / 128, 5), 512, 0, stream>>>(feat_bf, w1s, hb16, sum_, sumsq_);
    k_split_h<<<1280, 256, 0, stream>>>(hb16, sum_, sumsq_, gamma, beta, ht_hi);
    k_fused<<<1024, 512, 0, stream>>>(ht_hi, w2t, b2, x, out);
}